// Round 8
// baseline (607.986 us; speedup 1.0000x reference)
//
#include <hip/hip_runtime.h>
#include <math.h>

// Problem constants
#define B_   4
#define S_   2048
#define D_   1024
#define H_   16
#define HD_  64
#define C_   10
#define FFN_ 2048
#define M_   (B_ * S_)   // 8192 tokens
#define D3_  (3 * D_)    // 3072

typedef unsigned short u16;
typedef __bf16 bf16x8 __attribute__((ext_vector_type(8)));
typedef float  f32x4  __attribute__((ext_vector_type(4)));

#define EXPSCL 0.18033688011112042f   // 0.125 * log2(e), folded into Q

__device__ __forceinline__ u16 f2bf(float f) {
  union { float f; unsigned u; } x; x.f = f;
  unsigned r = x.u + 0x7fffu + ((x.u >> 16) & 1u);  // RNE
  return (u16)(r >> 16);
}
// pack 2 floats -> 2 bf16 (RNE) in ONE VALU op
__device__ __forceinline__ unsigned cvtpk(float lo, float hi) {
  unsigned r;
  asm("v_cvt_pk_bf16_f32 %0, %1, %2" : "=v"(r) : "v"(lo), "v"(hi));
  return r;
}
__device__ __forceinline__ float gelu_f(float x) {
  return 0.5f * x * (1.f + erff(x * 0.70710678118654752440f));
}
// async global->LDS, 16B per lane; LDS dest = wave-uniform base + lane*16
__device__ __forceinline__ void gload_lds16(const void* g, void* l) {
  __builtin_amdgcn_global_load_lds(
      (const __attribute__((address_space(1))) unsigned int*)g,
      (__attribute__((address_space(3))) unsigned int*)l, 16, 0, 0);
}
// LDS tile row-major stride 64 elems, 16B blocks XOR-swizzled by (row&7).
__device__ __forceinline__ bf16x8 ldsfrag(const u16* buf, int rowbase, int fr, int kb) {
  return *(const bf16x8*)&buf[(rowbase + fr) * 64 + ((kb ^ (fr & 7)) << 3)];
}

// ---------------------------------------------------------------------------
// FUSED: fp32 -> bf16 convert of all 4 weight matrices + embedding/posenc.
#define CV0 786432   // qkv_w  f32x4 count (3M elems)
#define CV1 262144   // fc_w   (1M)
#define CV2 524288   // ffn_w1 (2M)
#define CV3 524288   // ffn_w2 (2M)
__global__ __launch_bounds__(256) void prep_kernel(const float* __restrict__ s0,
                                                   const float* __restrict__ s1,
                                                   const float* __restrict__ s2,
                                                   const float* __restrict__ s3,
                                                   u16* __restrict__ d0,
                                                   u16* __restrict__ d1,
                                                   u16* __restrict__ d2,
                                                   u16* __restrict__ d3,
                                                   const int* __restrict__ ids,
                                                   const float* __restrict__ emb,
                                                   float* __restrict__ resid,
                                                   u16* __restrict__ xb) {
  if (blockIdx.x < 8192) {   // ---- weight convert ----
    int v = blockIdx.x * 256 + threadIdx.x;
    const float* s; u16* d;
    if (v < CV0) { s = s0; d = d0; }
    else if (v < CV0 + CV1) { s = s1; d = d1; v -= CV0; }
    else if (v < CV0 + CV1 + CV2) { s = s2; d = d2; v -= CV0 + CV1; }
    else { s = s3; d = d3; v -= CV0 + CV1 + CV2; }
    const int i = v * 4;
    f32x4 x = *(const f32x4*)&s[i];
    ushort4 o;
    o.x = f2bf(x[0]); o.y = f2bf(x[1]); o.z = f2bf(x[2]); o.w = f2bf(x[3]);
    *(ushort4*)&d[i] = o;
  } else {                   // ---- embed + posenc ----
    const int m  = blockIdx.x - 8192;
    const int s  = m & (S_ - 1);
    const int id = ids[m];
    const int d4 = threadIdx.x * 4;
    const f32x4 e = *(const f32x4*)&emb[(size_t)id * D_ + d4];
    const float fs = (float)s;
    const float f0 = __expf((float)d4 * (-9.210340371976184f / 1024.0f));
    const float f1 = __expf((float)(d4 + 2) * (-9.210340371976184f / 1024.0f));
    float s0v, c0v, s1v, c1v;
    __sincosf(fs * f0, &s0v, &c0v);
    __sincosf(fs * f1, &s1v, &c1v);
    f32x4 v;
    v[0] = e[0] + s0v; v[1] = e[1] + c0v; v[2] = e[2] + s1v; v[3] = e[3] + c1v;
    *(f32x4*)&resid[(size_t)m * D_ + d4] = v;
    ushort4 pk;
    pk.x = f2bf(v[0]); pk.y = f2bf(v[1]); pk.z = f2bf(v[2]); pk.w = f2bf(v[3]);
    *(ushort4*)&xb[(size_t)m * D_ + d4] = pk;
  }
}

// ---------------------------------------------------------------------------
// 256x256 8-phase counted-vmcnt bf16 GEMM (T3+T4 template, m198/m201 family).
// 512 thr = 8 waves (2M x 4N), per-wave C = 128x64 (acc[8][4] f32x4).
// LDS = 2 buffers x (A 2x[128][64] + B 2x[128][64]) = 128 KiB, our proven
// row&7 16B-block XOR swizzle (pre-swizzled global src for gload_lds,
// swizzled ldsfrag read -- both-sides-consistent, rule 21).
// Schedule per K-tile g (buf b=g&1), 4 phases x {frag ds_reads + stage one
// half-tile -> s_barrier -> lgkmcnt(0)+sched_barrier -> 16 MFMA -> s_barrier}:
//   ph0 stages T(g+1).Ah0 (buf b^1; its A-region was drained end of group g-1)
//   ph1 stages T(g+1).Ah1
//   ph2 stages T(g+2).Bh0 (buf b; B-region drained at ph0's lgkmcnt)
//   ph3 stages T(g+2).Bh1, then vmcnt(4) (= T(g+1).B events still in flight)
// so tile g+1 is guaranteed landed at the group boundary. vmcnt never 0 in
// the main loop (T4); raw s_barrier (no implicit drain).
// B-frags register-cached per K-tile (read once at ph0).
template <int BIAS, int GELU, int QSCALE, int VSPLIT>
__global__ __launch_bounds__(512) void gemm256(const u16* __restrict__ A,
                                               const u16* __restrict__ W,
                                               const float* __restrict__ bias,
                                               u16* __restrict__ outb,
                                               u16* __restrict__ vtout,
                                               int M, int N, int K) {
  __shared__ u16 lds[2][4][128 * 64];   // [buf][Ah0,Ah1,Bh0,Bh1] = 128 KiB
  const int tid = threadIdx.x, lane = tid & 63, w = tid >> 6;  // w = 0..7
  const int nx = gridDim.x, nwg = nx * gridDim.y;              // nwg % 8 == 0
  int t = blockIdx.y * nx + blockIdx.x;
  t = (t & 7) * (nwg >> 3) + (t >> 3);                         // XCD chunk
  const int bx = t % nx, by = t / nx;
  const int l3 = lane >> 3, sb = (lane & 7) ^ l3;
  const int fr = lane & 15, fq = lane >> 4;
  const int wm = w >> 2, wn = w & 3;
  const u16* Ag = A + (size_t)(by * 256 + w * 16 + l3) * K + sb * 8;
  const u16* Wg = W + (size_t)(bx * 256 + w * 16 + l3) * K + sb * 8;
  const int NT = K >> 6;

  // stage one 128-row half-tile (16 KiB): each wave covers rows w*16..+15
#define ST_A(tt, bb, h)                                                       \
  do {                                                                        \
    const u16* g_ = Ag + (size_t)((h) * 128) * K + (size_t)(tt) * 64;         \
    gload_lds16(g_, &lds[bb][h][(w * 16) * 64]);                              \
    gload_lds16(g_ + (size_t)8 * K, &lds[bb][h][(w * 16 + 8) * 64]);          \
  } while (0)
#define ST_B(tt, bb, h)                                                       \
  do {                                                                        \
    const u16* g_ = Wg + (size_t)((h) * 128) * K + (size_t)(tt) * 64;         \
    gload_lds16(g_, &lds[bb][2 + (h)][(w * 16) * 64]);                        \
    gload_lds16(g_ + (size_t)8 * K, &lds[bb][2 + (h)][(w * 16 + 8) * 64]);    \
  } while (0)

  // prologue: T0 fully (8 events/wave) + T1.B (4 events/wave)
  ST_A(0, 0, 0); ST_A(0, 0, 1); ST_B(0, 0, 0); ST_B(0, 0, 1);
  ST_B(1, 1, 0); ST_B(1, 1, 1);
  asm volatile("s_waitcnt vmcnt(4)" ::: "memory");   // oldest 8 (= T0) landed
  __builtin_amdgcn_s_barrier();

  f32x4 acc[8][4] = {};
  bf16x8 bf[4][2];
  const int cb = (wn & 1) * 64;

#define PHASE(p, ...)                                                         \
  {                                                                           \
    if ((p) == 0) {                                                           \
      _Pragma("unroll") for (int n = 0; n < 4; ++n) {                         \
        _Pragma("unroll") for (int kk = 0; kk < 2; ++kk) {                    \
          bf[n][kk] = ldsfrag(Bs_, cb + n * 16, fr, kk * 4 + fq);             \
        }                                                                     \
      }                                                                       \
    }                                                                         \
    bf16x8 af[2][2];                                                          \
    _Pragma("unroll") for (int mm = 0; mm < 2; ++mm) {                        \
      _Pragma("unroll") for (int kk = 0; kk < 2; ++kk) {                      \
        af[mm][kk] = ldsfrag(As_, (2 * (p) + mm) * 16, fr, kk * 4 + fq);      \
      }                                                                       \
    }                                                                         \
    __VA_ARGS__;                                                              \
    __builtin_amdgcn_s_barrier();                                             \
    asm volatile("s_waitcnt lgkmcnt(0)" ::: "memory");                        \
    __builtin_amdgcn_sched_barrier(0);                                        \
    __builtin_amdgcn_s_setprio(1);                                            \
    _Pragma("unroll") for (int mm = 0; mm < 2; ++mm) {                        \
      _Pragma("unroll") for (int n = 0; n < 4; ++n) {                         \
        _Pragma("unroll") for (int kk = 0; kk < 2; ++kk) {                    \
          acc[2 * (p) + mm][n] = __builtin_amdgcn_mfma_f32_16x16x32_bf16(     \
              bf[n][kk], af[mm][kk], acc[2 * (p) + mm][n], 0, 0, 0);          \
        }                                                                     \
      }                                                                       \
    }                                                                         \
    __builtin_amdgcn_s_setprio(0);                                            \
  }

  for (int g = 0; g < NT; ++g) {
    const int b = g & 1;
    const u16* As_ = lds[b][wm];
    const u16* Bs_ = lds[b][2 + (wn >> 1)];

    PHASE(0, if (g + 1 < NT) ST_A(g + 1, b ^ 1, 0));
    __builtin_amdgcn_s_barrier();
    PHASE(1, if (g + 1 < NT) ST_A(g + 1, b ^ 1, 1));
    __builtin_amdgcn_s_barrier();
    PHASE(2, if (g + 2 < NT) ST_B(g + 2, b, 0));
    __builtin_amdgcn_s_barrier();
    PHASE(3, if (g + 2 < NT) ST_B(g + 2, b, 1));
    if (g + 1 < NT) {
      if (g + 2 < NT) { asm volatile("s_waitcnt vmcnt(4)" ::: "memory"); }
      else            { asm volatile("s_waitcnt vmcnt(0)" ::: "memory"); }
    }
    __builtin_amdgcn_s_barrier();
  }
#undef PHASE
#undef ST_A
#undef ST_B

  // epilogue: C^T frags -> mrow = lane fr, ncol = fq*4 + reg (as gemm_bt)
  const float qs = (QSCALE && bx < 4) ? EXPSCL : 1.f;
#pragma unroll
  for (int m = 0; m < 8; ++m) {
    const int mrow = by * 256 + wm * 128 + m * 16 + fr;
#pragma unroll
    for (int n = 0; n < 4; ++n) {
      const int ncol = bx * 256 + wn * 64 + n * 16 + fq * 4;
      f32x4 v = acc[m][n];
      if (BIAS) v += *(const f32x4*)&bias[ncol];
      if (GELU) {
        v[0] = gelu_f(v[0]); v[1] = gelu_f(v[1]);
        v[2] = gelu_f(v[2]); v[3] = gelu_f(v[3]);
      }
      if (QSCALE) v *= qs;
      if (VSPLIT && bx >= 8) {
        // V column: write transposed to vt[b][h][d][s]
        const int hh = (ncol - 2 * D_) >> 6;
        const int dl = (ncol - 2 * D_) & 63;     // dl..dl+3 stay in one h
        const int bb2 = mrow >> 11, ss = mrow & (S_ - 1);
        u16* vdst = vtout + ((size_t)((bb2 * H_ + hh) * 64 + dl)) * S_ + ss;
        vdst[0]              = f2bf(v[0]);
        vdst[(size_t)S_]     = f2bf(v[1]);
        vdst[(size_t)2 * S_] = f2bf(v[2]);
        vdst[(size_t)3 * S_] = f2bf(v[3]);
      } else {
        ushort4 pk;
        pk.x = f2bf(v[0]); pk.y = f2bf(v[1]); pk.z = f2bf(v[2]); pk.w = f2bf(v[3]);
        *(ushort4*)&outb[(size_t)mrow * N + ncol] = pk;
      }
    }
  }
}

// ---------------------------------------------------------------------------
// bf16 MFMA GEMM (m97-family 128x128), kept for the N=1024 fp32-out GEMMs
// (fc, FFN2) where a 256-tile grid would fill only half the CUs.
template <int BIAS, int GELU, int OUTBF, int QSCALE, int VSPLIT>
__global__ __launch_bounds__(256) void gemm_bt(const u16* __restrict__ A,
                                               const u16* __restrict__ W,
                                               const float* __restrict__ bias,
                                               float* __restrict__ outf,
                                               u16* __restrict__ outb,
                                               u16* __restrict__ vtout,
                                               int M, int N, int K) {
  __shared__ u16 As[128 * 64];
  __shared__ u16 Bs[128 * 64];
  const int tid  = threadIdx.x;
  const int lane = tid & 63;
  const int w    = tid >> 6;
  const int nx  = gridDim.x;
  const int nwg = nx * gridDim.y;              // % 8 == 0 for all launches
  int t = blockIdx.y * nx + blockIdx.x;
  t = (t & 7) * (nwg >> 3) + (t >> 3);
  const int bx = t % nx, by = t / nx;
  const int l3   = lane >> 3;              // row within 8-row gload group
  const int sb   = (lane & 7) ^ l3;        // swizzled source 16B block
  const u16* Ag0 = A + (size_t)(by * 128 + w * 32 + l3) * K + sb * 8;
  const u16* Wg0 = W + (size_t)(bx * 128 + w * 32 + l3) * K + sb * 8;

  f32x4 acc[4][4] = {};
  const int wr  = (w & 1) * 64;
  const int wc  = (w >> 1) * 64;
  const int fr  = lane & 15;
  const int fq  = lane >> 4;

  for (int kt = 0; kt < K; kt += 64) {
#pragma unroll
    for (int c = 0; c < 4; ++c) {
      gload_lds16(Ag0 + (size_t)(c * 8) * K + kt, &As[(w * 32 + c * 8) * 64]);
      gload_lds16(Wg0 + (size_t)(c * 8) * K + kt, &Bs[(w * 32 + c * 8) * 64]);
    }
    __syncthreads();  // drains vmcnt -> LDS tiles visible
#pragma unroll
    for (int ks = 0; ks < 2; ++ks) {
      const int kb = ks * 4 + fq;
      bf16x8 af[4], bfr[4];
#pragma unroll
      for (int i = 0; i < 4; ++i) af[i] = ldsfrag(As, wr + i * 16, fr, kb);
#pragma unroll
      for (int j = 0; j < 4; ++j) bfr[j] = ldsfrag(Bs, wc + j * 16, fr, kb);
#pragma unroll
      for (int i = 0; i < 4; ++i)
#pragma unroll
        for (int j = 0; j < 4; ++j)
          acc[i][j] = __builtin_amdgcn_mfma_f32_16x16x32_bf16(bfr[j], af[i], acc[i][j], 0, 0, 0);
    }
    __syncthreads();  // all reads done before next overwrite
  }

  const float qs = (QSCALE && bx < 8) ? EXPSCL : 1.f;
#pragma unroll
  for (int i = 0; i < 4; ++i) {
    const int m = by * 128 + wr + i * 16 + fr;
#pragma unroll
    for (int j = 0; j < 4; ++j) {
      const int nb = bx * 128 + wc + j * 16 + fq * 4;
      f32x4 v = acc[i][j];
      if (BIAS) v += *(const f32x4*)&bias[nb];
      if (GELU) {
        v[0] = gelu_f(v[0]); v[1] = gelu_f(v[1]);
        v[2] = gelu_f(v[2]); v[3] = gelu_f(v[3]);
      }
      if (QSCALE) v *= qs;
      if (VSPLIT && bx >= 16) {
        const int hh = (nb - 2 * D_) >> 6;
        const int dl = (nb - 2 * D_) & 63;
        const int bb = m >> 11, ss = m & (S_ - 1);
        u16* vdst = vtout + ((size_t)((bb * H_ + hh) * 64 + dl)) * S_ + ss;
        vdst[0]          = f2bf(v[0]);
        vdst[(size_t)S_]     = f2bf(v[1]);
        vdst[(size_t)2 * S_] = f2bf(v[2]);
        vdst[(size_t)3 * S_] = f2bf(v[3]);
      } else if (OUTBF) {
        ushort4 pk;
        pk.x = f2bf(v[0]); pk.y = f2bf(v[1]); pk.z = f2bf(v[2]); pk.w = f2bf(v[3]);
        *(ushort4*)&outb[(size_t)m * N + nb] = pk;
      } else {
        *(f32x4*)&outf[(size_t)m * N + nb] = v;
      }
    }
  }
}

// ---------------------------------------------------------------------------
// MFMA flash attention, 8 waves x 16 q-rows (512 thr), NO-MAX softmax.
// r7's measured-best body (136 us), unchanged.
__global__ __launch_bounds__(512) void attn_mfma_kernel(const u16* __restrict__ qkv,
                                                        const u16* __restrict__ vt,
                                                        const int* __restrict__ mask,
                                                        u16* __restrict__ attno) {
  __shared__ u16 Ks[64 * 64];     // 8K
  __shared__ u16 Vts[64 * 64];    // 8K
  __shared__ u16 Ps[8][16 * 64];  // 16K  -> total 32768 B
  const int tid = threadIdx.x, lane = tid & 63, w = tid >> 6;  // w = 0..7
  int t = (blockIdx.z * 16 + blockIdx.y) * 16 + blockIdx.x;
  t = (t & 7) * 128 + (t >> 3);
  const int qt = t & 15, h = (t >> 4) & 15, b = t >> 8;
  const int l3 = lane >> 3;
  const int sb = (lane & 7) ^ l3;
  const int fr = lane & 15, fq = lane >> 4;
  u16* PsFlat = &Ps[0][0];

  {
    const u16* qbase = qkv + (size_t)(b * S_ + qt * 128 + w * 16) * D3_ + h * 64 + sb * 8;
    gload_lds16(qbase + (size_t)l3 * D3_, &PsFlat[(w * 16) * 64]);
    gload_lds16(qbase + (size_t)(8 + l3) * D3_, &PsFlat[(w * 16 + 8) * 64]);
  }

  bool ALLV;
  {
    const int4* mp = (const int4*)&mask[b * S_];
    int mv = 1;
#pragma unroll
    for (int tt = 0; tt < 8; ++tt) {
      const int4 m4 = mp[tt * 64 + lane];
      mv &= (m4.x != 0) & (m4.y != 0) & (m4.z != 0) & (m4.w != 0);
    }
    ALLV = (__ballot(mv != 0) == ~0ull);
  }

  __syncthreads();

  bf16x8 qf[2];
#pragma unroll
  for (int ks = 0; ks < 2; ++ks)
    qf[ks] = ldsfrag(PsFlat, w * 16, fr, ks * 4 + fq);

  __syncthreads();

  float l_st = 0.f;
  f32x4 ot[4] = {};
  u16* PsW = Ps[w];

  for (int kt = 0; kt < S_ / 64; ++kt) {
    {
      const u16* kbase = qkv + (size_t)(b * S_ + kt * 64 + w * 8 + l3) * D3_ + D_ + h * 64 + sb * 8;
      gload_lds16(kbase, &Ks[(w * 8) * 64]);
      const u16* vbase = vt + ((size_t)((b * H_ + h) * 64 + w * 8 + l3)) * S_ + kt * 64 + sb * 8;
      gload_lds16(vbase, &Vts[(w * 8) * 64]);
    }
    __syncthreads();

    f32x4 sf[4] = {};
#pragma unroll
    for (int ks = 0; ks < 2; ++ks) {
      const int kb = ks * 4 + fq;
      __builtin_amdgcn_s_setprio(1);
#pragma unroll
      for (int r4 = 0; r4 < 4; ++r4) {
        bf16x8 kf = ldsfrag(Ks, r4 * 16, fr, kb);
        sf[r4] = __builtin_amdgcn_mfma_f32_16x16x32_bf16(kf, qf[ks], sf[r4], 0, 0, 0);
      }
      __builtin_amdgcn_s_setprio(0);
    }
    if (!ALLV) {
#pragma unroll
      for (int r4 = 0; r4 < 4; ++r4) {
        const int4 mm = *(const int4*)&mask[b * S_ + kt * 64 + r4 * 16 + fq * 4];
        f32x4 vb;
        vb[0] = mm.x ? 0.f : -1e30f;
        vb[1] = mm.y ? 0.f : -1e30f;
        vb[2] = mm.z ? 0.f : -1e30f;
        vb[3] = mm.w ? 0.f : -1e30f;
        sf[r4] += vb;
      }
    }

    {
      u16* pw = PsW + fr * 64;
      float sum = l_st;
#pragma unroll
      for (int r4 = 0; r4 < 4; ++r4) {
        const float p0 = __builtin_exp2f(sf[r4][0]);
        const float p1 = __builtin_exp2f(sf[r4][1]);
        const float p2 = __builtin_exp2f(sf[r4][2]);
        const float p3 = __builtin_exp2f(sf[r4][3]);
        sum += (p0 + p1) + (p2 + p3);
        const int bk0 = 2 * r4 + (fq >> 1);
        const int off = ((bk0 ^ (fr & 7)) << 3) + ((fq & 1) << 2);
        uint2 pk; pk.x = cvtpk(p0, p1); pk.y = cvtpk(p2, p3);
        *(uint2*)&pw[off] = pk;
      }
      l_st = sum;
    }
    asm volatile("s_waitcnt lgkmcnt(0)" ::: "memory");

#pragma unroll
    for (int ks = 0; ks < 2; ++ks) {
      const int kb = ks * 4 + fq;
      bf16x8 pf = ldsfrag(PsW, 0, fr, kb);
      __builtin_amdgcn_s_setprio(1);
#pragma unroll
      for (int db = 0; db < 4; ++db) {
        bf16x8 vf = ldsfrag(Vts, db * 16, fr, kb);
        ot[db] = __builtin_amdgcn_mfma_f32_16x16x32_bf16(vf, pf, ot[db], 0, 0, 0);
      }
      __builtin_amdgcn_s_setprio(0);
    }
    __syncthreads();
  }

  {
    float l = l_st;
    l += __shfl_xor(l, 16);
    l += __shfl_xor(l, 32);
    const float inv = (l > 0.f) ? 1.f / l : 0.f;
    const int qrow = qt * 128 + w * 16 + fr;
    u16* dst = attno + (size_t)(b * S_ + qrow) * D_ + h * 64 + fq * 4;
#pragma unroll
    for (int db = 0; db < 4; ++db) {
      ushort4 pk;
      pk.x = f2bf(ot[db][0] * inv);
      pk.y = f2bf(ot[db][1] * inv);
      pk.z = f2bf(ot[db][2] * inv);
      pk.w = f2bf(ot[db][3] * inv);
      *(ushort4*)&dst[db * 16] = pk;
    }
  }
}

// ---------------------------------------------------------------------------
// LayerNorm(a + res) * g + be  ->  fp32 out (+ optional bf16 copy).
template <int WRITEB>
__global__ __launch_bounds__(256) void ln_kernel(const float* __restrict__ a,
                                                 const float* __restrict__ res,
                                                 const float* __restrict__ g,
                                                 const float* __restrict__ be,
                                                 float* __restrict__ outf,
                                                 u16* __restrict__ outb) {
  const int row = blockIdx.x, tid = threadIdx.x;
  const int lane = tid & 63, w = tid >> 6;
  const size_t base = (size_t)row * D_ + tid * 4;
  const f32x4 va = *(const f32x4*)(a + base);
  const f32x4 vr = *(const f32x4*)(res + base);
  const f32x4 v  = va + vr;
  float s = v[0] + v[1] + v[2] + v[3];
#pragma unroll
  for (int o = 32; o > 0; o >>= 1) s += __shfl_xor(s, o);
  __shared__ float red[8];
  if (lane == 0) red[w] = s;
  __syncthreads();
  const float mu = (red[0] + red[1] + red[2] + red[3]) * (1.f / D_);
  const f32x4 d = v - mu;
  float s2 = d[0] * d[0] + d[1] * d[1] + d[2] * d[2] + d[3] * d[3];
#pragma unroll
  for (int o = 32; o > 0; o >>= 1) s2 += __shfl_xor(s2, o);
  if (lane == 0) red[4 + w] = s2;
  __syncthreads();
  const float var = (red[4] + red[5] + red[6] + red[7]) * (1.f / D_);
  const float rs = rsqrtf(var + 1e-5f);
  f32x4 y;
#pragma unroll
  for (int k = 0; k < 4; ++k) {
    const int ch = tid * 4 + k;
    y[k] = d[k] * rs * g[ch] + be[ch];
  }
  *(f32x4*)&outf[base] = y;
  if (WRITEB) {
    ushort4 pk;
    pk.x = f2bf(y[0]); pk.y = f2bf(y[1]); pk.z = f2bf(y[2]); pk.w = f2bf(y[3]);
    *(ushort4*)&outb[base] = pk;
  }
}

// ---------------------------------------------------------------------------
// masked max-pool over sequence, two stages
__global__ __launch_bounds__(256) void pool_part_kernel(const float* __restrict__ x,
                                                        const int* __restrict__ mask,
                                                        float* __restrict__ part) {
  const int b = blockIdx.y, ch = blockIdx.x;
  const int d0 = threadIdx.x * 4;
  f32x4 acc = {-INFINITY, -INFINITY, -INFINITY, -INFINITY};
  for (int ss = 0; ss < 64; ++ss) {
    const int s = ch * 64 + ss;
    if (mask[b * S_ + s] != 0) {
      const f32x4 v = *(const f32x4*)&x[(size_t)(b * S_ + s) * D_ + d0];
      acc[0] = fmaxf(acc[0], v[0]);
      acc[1] = fmaxf(acc[1], v[1]);
      acc[2] = fmaxf(acc[2], v[2]);
      acc[3] = fmaxf(acc[3], v[3]);
    }
  }
  *(f32x4*)&part[(size_t)(b * 32 + ch) * D_ + d0] = acc;
}
__global__ __launch_bounds__(256) void pool_final_kernel(const float* __restrict__ part,
                                                         float* __restrict__ pooled) {
  const int b = blockIdx.x;
  const int d0 = threadIdx.x * 4;
  f32x4 acc = {-INFINITY, -INFINITY, -INFINITY, -INFINITY};
  for (int ch = 0; ch < 32; ++ch) {
    const f32x4 v = *(const f32x4*)&part[(size_t)(b * 32 + ch) * D_ + d0];
    acc[0] = fmaxf(acc[0], v[0]);
    acc[1] = fmaxf(acc[1], v[1]);
    acc[2] = fmaxf(acc[2], v[2]);
    acc[3] = fmaxf(acc[3], v[3]);
  }
  *(f32x4*)&pooled[(size_t)b * D_ + d0] = acc;
}

// ---------------------------------------------------------------------------
// tiny head GEMMs in fp32, one wave per output element
__global__ __launch_bounds__(256) void head1_kernel(const float* __restrict__ pooled,
                                                    const float* __restrict__ w,
                                                    const float* __restrict__ bias,
                                                    float* __restrict__ hh) {
  const int lane = threadIdx.x & 63;
  const int gw = blockIdx.x * 4 + (threadIdx.x >> 6);
  const int b = gw >> 10, n = gw & 1023;
  const float* p  = pooled + b * 1024;
  const float* wr = w + (size_t)n * 1024;
  float s = 0.f;
  for (int d = lane; d < 1024; d += 64) s += p[d] * wr[d];
#pragma unroll
  for (int off = 32; off > 0; off >>= 1) s += __shfl_xor(s, off);
  if (lane == 0) hh[b * 1024 + n] = gelu_f(s + bias[n]);
}
__global__ __launch_bounds__(256) void head2_kernel(const float* __restrict__ hh,
                                                    const float* __restrict__ w,
                                                    const float* __restrict__ bias,
                                                    float* __restrict__ out) {
  const int lane = threadIdx.x & 63;
  const int gw = blockIdx.x * 4 + (threadIdx.x >> 6);  // 0..39
  const int b = gw / 10, c = gw % 10;
  const float* p  = hh + b * 1024;
  const float* wr = w + (size_t)c * 1024;
  float s = 0.f;
  for (int d = lane; d < 1024; d += 64) s += p[d] * wr[d];
#pragma unroll
  for (int off = 32; off > 0; off >>= 1) s += __shfl_xor(s, off);
  if (lane == 0) out[b * 10 + c] = s + bias[c];
}

// ---------------------------------------------------------------------------
// workspace layout (bytes)
#define OFF_RESID  0UL                      // 32 MB fp32 [M,D]
#define OFF_F1     33554432UL               // 32 MB fp32 [M,D]  (alias: vt 16MB)
#define OFF_XB     67108864UL               // 16 MB bf16 [M,D]
#define OFF_QKVB   83886080UL               // 48 MB bf16 [M,3D] (alias: hb 32MB)
#define OFF_ATTNO  134217728UL              // 16 MB bf16 [M,D]
#define OFF_WQKV   150994944UL              // 6 MB
#define OFF_WFC    157286400UL              // 2 MB
#define OFF_WF1    159383552UL              // 4 MB
#define OFF_WF2    163577856UL              // 4 MB
#define OFF_PART   167772160UL              // 512 KB
#define OFF_POOLED 168296448UL              // 16 KB
#define OFF_HH     168312832UL              // 16 KB  (end ~160.6 MB)

extern "C" void kernel_launch(void* const* d_in, const int* in_sizes, int n_in,
                              void* d_out, int out_size, void* d_ws, size_t ws_size,
                              hipStream_t stream) {
  const int*   x_ids  = (const int*)d_in[0];
  const int*   mask   = (const int*)d_in[1];
  const float* emb    = (const float*)d_in[2];
  const float* qkv_w  = (const float*)d_in[3];
  const float* fc_w   = (const float*)d_in[4];
  const float* fc_b   = (const float*)d_in[5];
  const float* ln1_g  = (const float*)d_in[6];
  const float* ln1_b  = (const float*)d_in[7];
  const float* ffn_w1 = (const float*)d_in[8];
  const float* ffn_b1 = (const float*)d_in[9];
  const float* ffn_w2 = (const float*)d_in[10];
  const float* ffn_b2 = (const float*)d_in[11];
  const float* ln2_g  = (const float*)d_in[12];
  const float* ln2_b  = (const float*)d_in[13];
  const float* pr_w1  = (const float*)d_in[14];
  const float* pr_b1  = (const float*)d_in[15];
  const float* pr_w2  = (const float*)d_in[16];
  const float* pr_b2  = (const float*)d_in[17];
  float* out = (float*)d_out;
  char* ws = (char*)d_ws;

  float* resid  = (float*)(ws + OFF_RESID);
  float* f1     = (float*)(ws + OFF_F1);
  u16*   vtb    = (u16*)(ws + OFF_F1);     // alias (dead before f1 written)
  u16*   xb     = (u16*)(ws + OFF_XB);
  u16*   qkvb   = (u16*)(ws + OFF_QKVB);
  u16*   hb     = (u16*)(ws + OFF_QKVB);   // alias
  u16*   attnob = (u16*)(ws + OFF_ATTNO);
  u16*   wqkvb  = (u16*)(ws + OFF_WQKV);
  u16*   wfcb   = (u16*)(ws + OFF_WFC);
  u16*   wf1b   = (u16*)(ws + OFF_WF1);
  u16*   wf2b   = (u16*)(ws + OFF_WF2);
  float* part   = (float*)(ws + OFF_PART);
  float* pooled = (float*)(ws + OFF_POOLED);
  float* hh     = (float*)(ws + OFF_HH);

  // weights fp32 -> bf16 + embed/posenc (single fused launch)
  prep_kernel<<<16384, 256, 0, stream>>>(qkv_w, fc_w, ffn_w1, ffn_w2,
                                         wqkvb, wfcb, wf1b, wf2b,
                                         x_ids, emb, resid, xb);

  // QKV projection: 256x256 8-phase GEMM (Q pre-scaled, V written transposed)
  gemm256<0, 0, 1, 1><<<dim3(D3_ / 256, M_ / 256), 512, 0, stream>>>(
      xb, wqkvb, nullptr, qkvb, vtb, M_, D3_, D_);

  attn_mfma_kernel<<<dim3(S_ / 128, H_, B_), 512, 0, stream>>>(qkvb, vtb, mask, attnob);

  // out proj (+bias) -> fp32  (128-tile: 256-tile grid would half-fill GPU)
  gemm_bt<1, 0, 0, 0, 0><<<dim3(D_ / 128, M_ / 128), 256, 0, stream>>>(
      attnob, wfcb, fc_b, f1, nullptr, nullptr, M_, D_, D_);

  // LN1(fc_out + resid) -> resid (fp32) + xb (bf16)
  ln_kernel<1><<<M_, 256, 0, stream>>>(f1, resid, ln1_g, ln1_b, resid, xb);

  // FFN1 (+bias, gelu) -> bf16 hb : 256x256 8-phase GEMM (grid 256 = exact fit)
  gemm256<1, 1, 0, 0><<<dim3(FFN_ / 256, M_ / 256), 512, 0, stream>>>(
      xb, wf1b, ffn_b1, hb, nullptr, M_, FFN_, D_);

  // FFN2 (+bias) -> fp32 f1
  gemm_bt<1, 0, 0, 0, 0><<<dim3(D_ / 128, M_ / 128), 256, 0, stream>>>(
      hb, wf2b, ffn_b2, f1, nullptr, nullptr, M_, D_, FFN_);

  // LN2(ffn_out + x1) -> f1 (fp32 only)
  ln_kernel<0><<<M_, 256, 0, stream>>>(f1, resid, ln2_g, ln2_b, f1, nullptr);

  // masked max-pool over S
  pool_part_kernel<<<dim3(32, B_), 256, 0, stream>>>(f1, mask, part);
  pool_final_kernel<<<B_, 256, 0, stream>>>(part, pooled);

  // prediction head (fp32)
  head1_kernel<<<1024, 256, 0, stream>>>(pooled, pr_w1, pr_b1, hh);
  head2_kernel<<<10, 256, 0, stream>>>(hh, pr_w2, pr_b2, out);
}

// Round 9
// 579.552 us; speedup vs baseline: 1.0491x; 1.0491x over previous
//
#include <hip/hip_runtime.h>
#include <math.h>

// Problem constants
#define B_   4
#define S_   2048
#define D_   1024
#define H_   16
#define HD_  64
#define C_   10
#define FFN_ 2048
#define M_   (B_ * S_)   // 8192 tokens
#define D3_  (3 * D_)    // 3072

typedef unsigned short u16;
typedef __bf16 bf16x8 __attribute__((ext_vector_type(8)));
typedef float  f32x4  __attribute__((ext_vector_type(4)));

#define EXPSCL 0.18033688011112042f   // 0.125 * log2(e), folded into Q

__device__ __forceinline__ u16 f2bf(float f) {
  union { float f; unsigned u; } x; x.f = f;
  unsigned r = x.u + 0x7fffu + ((x.u >> 16) & 1u);  // RNE
  return (u16)(r >> 16);
}
// pack 2 floats -> 2 bf16 (RNE) in ONE VALU op
__device__ __forceinline__ unsigned cvtpk(float lo, float hi) {
  unsigned r;
  asm("v_cvt_pk_bf16_f32 %0, %1, %2" : "=v"(r) : "v"(lo), "v"(hi));
  return r;
}
__device__ __forceinline__ float gelu_f(float x) {
  return 0.5f * x * (1.f + erff(x * 0.70710678118654752440f));
}
// async global->LDS, 16B per lane; LDS dest = wave-uniform base + lane*16
__device__ __forceinline__ void gload_lds16(const void* g, void* l) {
  __builtin_amdgcn_global_load_lds(
      (const __attribute__((address_space(1))) unsigned int*)g,
      (__attribute__((address_space(3))) unsigned int*)l, 16, 0, 0);
}
// LDS tile row-major stride 64 elems, 16B blocks XOR-swizzled by (row&7).
__device__ __forceinline__ bf16x8 ldsfrag(const u16* buf, int rowbase, int fr, int kb) {
  return *(const bf16x8*)&buf[(rowbase + fr) * 64 + ((kb ^ (fr & 7)) << 3)];
}

// ---------------------------------------------------------------------------
// FUSED: fp32 -> bf16 convert of all 4 weight matrices + embedding/posenc.
#define CV0 786432   // qkv_w  f32x4 count (3M elems)
#define CV1 262144   // fc_w   (1M)
#define CV2 524288   // ffn_w1 (2M)
#define CV3 524288   // ffn_w2 (2M)
__global__ __launch_bounds__(256) void prep_kernel(const float* __restrict__ s0,
                                                   const float* __restrict__ s1,
                                                   const float* __restrict__ s2,
                                                   const float* __restrict__ s3,
                                                   u16* __restrict__ d0,
                                                   u16* __restrict__ d1,
                                                   u16* __restrict__ d2,
                                                   u16* __restrict__ d3,
                                                   const int* __restrict__ ids,
                                                   const float* __restrict__ emb,
                                                   float* __restrict__ resid,
                                                   u16* __restrict__ xb) {
  if (blockIdx.x < 8192) {   // ---- weight convert ----
    int v = blockIdx.x * 256 + threadIdx.x;
    const float* s; u16* d;
    if (v < CV0) { s = s0; d = d0; }
    else if (v < CV0 + CV1) { s = s1; d = d1; v -= CV0; }
    else if (v < CV0 + CV1 + CV2) { s = s2; d = d2; v -= CV0 + CV1; }
    else { s = s3; d = d3; v -= CV0 + CV1 + CV2; }
    const int i = v * 4;
    f32x4 x = *(const f32x4*)&s[i];
    ushort4 o;
    o.x = f2bf(x[0]); o.y = f2bf(x[1]); o.z = f2bf(x[2]); o.w = f2bf(x[3]);
    *(ushort4*)&d[i] = o;
  } else {                   // ---- embed + posenc ----
    const int m  = blockIdx.x - 8192;
    const int s  = m & (S_ - 1);
    const int id = ids[m];
    const int d4 = threadIdx.x * 4;
    const f32x4 e = *(const f32x4*)&emb[(size_t)id * D_ + d4];
    const float fs = (float)s;
    const float f0 = __expf((float)d4 * (-9.210340371976184f / 1024.0f));
    const float f1 = __expf((float)(d4 + 2) * (-9.210340371976184f / 1024.0f));
    float s0v, c0v, s1v, c1v;
    __sincosf(fs * f0, &s0v, &c0v);
    __sincosf(fs * f1, &s1v, &c1v);
    f32x4 v;
    v[0] = e[0] + s0v; v[1] = e[1] + c0v; v[2] = e[2] + s1v; v[3] = e[3] + c1v;
    *(f32x4*)&resid[(size_t)m * D_ + d4] = v;
    ushort4 pk;
    pk.x = f2bf(v[0]); pk.y = f2bf(v[1]); pk.z = f2bf(v[2]); pk.w = f2bf(v[3]);
    *(ushort4*)&xb[(size_t)m * D_ + d4] = pk;
  }
}

// ---------------------------------------------------------------------------
// bf16 MFMA GEMM, TRANSPOSED accumulation (C^T per wave). 128x128 tile,
// BK=64, 256 thr, XOR-swizzled LDS, global_load_lds width 16.
// (r6 config restored: gemm256 measured neutral at these shapes, dropped.)
// XCD-chunked block swizzle (T1): bijective since all grids have nwg%8==0.
// QSCALE: Q columns (bx<8) pre-multiplied by EXPSCL = 0.125*log2(e).
// VSPLIT (QKV only): V columns (bx>=16) written TRANSPOSED to vt[b][h][d][s].
template <int BIAS, int GELU, int OUTBF, int QSCALE, int VSPLIT>
__global__ __launch_bounds__(256) void gemm_bt(const u16* __restrict__ A,
                                               const u16* __restrict__ W,
                                               const float* __restrict__ bias,
                                               float* __restrict__ outf,
                                               u16* __restrict__ outb,
                                               u16* __restrict__ vtout,
                                               int M, int N, int K) {
  __shared__ u16 As[128 * 64];
  __shared__ u16 Bs[128 * 64];
  const int tid  = threadIdx.x;
  const int lane = tid & 63;
  const int w    = tid >> 6;
  const int nx  = gridDim.x;
  const int nwg = nx * gridDim.y;              // % 8 == 0 for all launches
  int t = blockIdx.y * nx + blockIdx.x;
  t = (t & 7) * (nwg >> 3) + (t >> 3);
  const int bx = t % nx, by = t / nx;
  const int l3   = lane >> 3;              // row within 8-row gload group
  const int sb   = (lane & 7) ^ l3;        // swizzled source 16B block
  const u16* Ag0 = A + (size_t)(by * 128 + w * 32 + l3) * K + sb * 8;
  const u16* Wg0 = W + (size_t)(bx * 128 + w * 32 + l3) * K + sb * 8;

  f32x4 acc[4][4] = {};
  const int wr  = (w & 1) * 64;
  const int wc  = (w >> 1) * 64;
  const int fr  = lane & 15;
  const int fq  = lane >> 4;

  for (int kt = 0; kt < K; kt += 64) {
#pragma unroll
    for (int c = 0; c < 4; ++c) {
      gload_lds16(Ag0 + (size_t)(c * 8) * K + kt, &As[(w * 32 + c * 8) * 64]);
      gload_lds16(Wg0 + (size_t)(c * 8) * K + kt, &Bs[(w * 32 + c * 8) * 64]);
    }
    __syncthreads();  // drains vmcnt -> LDS tiles visible
#pragma unroll
    for (int ks = 0; ks < 2; ++ks) {
      const int kb = ks * 4 + fq;
      bf16x8 af[4], bfr[4];
#pragma unroll
      for (int i = 0; i < 4; ++i) af[i] = ldsfrag(As, wr + i * 16, fr, kb);
#pragma unroll
      for (int j = 0; j < 4; ++j) bfr[j] = ldsfrag(Bs, wc + j * 16, fr, kb);
#pragma unroll
      for (int i = 0; i < 4; ++i)
#pragma unroll
        for (int j = 0; j < 4; ++j)
          acc[i][j] = __builtin_amdgcn_mfma_f32_16x16x32_bf16(bfr[j], af[i], acc[i][j], 0, 0, 0);
    }
    __syncthreads();  // all reads done before next overwrite
  }

  const float qs = (QSCALE && bx < 8) ? EXPSCL : 1.f;
#pragma unroll
  for (int i = 0; i < 4; ++i) {
    const int m = by * 128 + wr + i * 16 + fr;
#pragma unroll
    for (int j = 0; j < 4; ++j) {
      const int nb = bx * 128 + wc + j * 16 + fq * 4;
      f32x4 v = acc[i][j];
      if (BIAS) v += *(const f32x4*)&bias[nb];
      if (GELU) {
        v[0] = gelu_f(v[0]); v[1] = gelu_f(v[1]);
        v[2] = gelu_f(v[2]); v[3] = gelu_f(v[3]);
      }
      if (QSCALE) v *= qs;
      if (VSPLIT && bx >= 16) {
        const int hh = (nb - 2 * D_) >> 6;
        const int dl = (nb - 2 * D_) & 63;
        const int bb = m >> 11, ss = m & (S_ - 1);
        u16* vdst = vtout + ((size_t)((bb * H_ + hh) * 64 + dl)) * S_ + ss;
        vdst[0]              = f2bf(v[0]);
        vdst[(size_t)S_]     = f2bf(v[1]);
        vdst[(size_t)2 * S_] = f2bf(v[2]);
        vdst[(size_t)3 * S_] = f2bf(v[3]);
      } else if (OUTBF) {
        ushort4 pk;
        pk.x = f2bf(v[0]); pk.y = f2bf(v[1]); pk.z = f2bf(v[2]); pk.w = f2bf(v[3]);
        *(ushort4*)&outb[(size_t)m * N + nb] = pk;
      } else {
        *(f32x4*)&outf[(size_t)m * N + nb] = v;
      }
    }
  }
}

// ---------------------------------------------------------------------------
// MFMA flash attention, 8 waves x 16 q-rows (512 thr), NO-MAX softmax.
// r7's measured-best body (133 us), unchanged.
__global__ __launch_bounds__(512) void attn_mfma_kernel(const u16* __restrict__ qkv,
                                                        const u16* __restrict__ vt,
                                                        const int* __restrict__ mask,
                                                        u16* __restrict__ attno) {
  __shared__ u16 Ks[64 * 64];     // 8K
  __shared__ u16 Vts[64 * 64];    // 8K
  __shared__ u16 Ps[8][16 * 64];  // 16K  -> total 32768 B
  const int tid = threadIdx.x, lane = tid & 63, w = tid >> 6;  // w = 0..7
  int t = (blockIdx.z * 16 + blockIdx.y) * 16 + blockIdx.x;
  t = (t & 7) * 128 + (t >> 3);
  const int qt = t & 15, h = (t >> 4) & 15, b = t >> 8;
  const int l3 = lane >> 3;
  const int sb = (lane & 7) ^ l3;
  const int fr = lane & 15, fq = lane >> 4;
  u16* PsFlat = &Ps[0][0];

  {
    const u16* qbase = qkv + (size_t)(b * S_ + qt * 128 + w * 16) * D3_ + h * 64 + sb * 8;
    gload_lds16(qbase + (size_t)l3 * D3_, &PsFlat[(w * 16) * 64]);
    gload_lds16(qbase + (size_t)(8 + l3) * D3_, &PsFlat[(w * 16 + 8) * 64]);
  }

  bool ALLV;
  {
    const int4* mp = (const int4*)&mask[b * S_];
    int mv = 1;
#pragma unroll
    for (int tt = 0; tt < 8; ++tt) {
      const int4 m4 = mp[tt * 64 + lane];
      mv &= (m4.x != 0) & (m4.y != 0) & (m4.z != 0) & (m4.w != 0);
    }
    ALLV = (__ballot(mv != 0) == ~0ull);
  }

  __syncthreads();

  bf16x8 qf[2];
#pragma unroll
  for (int ks = 0; ks < 2; ++ks)
    qf[ks] = ldsfrag(PsFlat, w * 16, fr, ks * 4 + fq);

  __syncthreads();

  float l_st = 0.f;
  f32x4 ot[4] = {};
  u16* PsW = Ps[w];

  for (int kt = 0; kt < S_ / 64; ++kt) {
    {
      const u16* kbase = qkv + (size_t)(b * S_ + kt * 64 + w * 8 + l3) * D3_ + D_ + h * 64 + sb * 8;
      gload_lds16(kbase, &Ks[(w * 8) * 64]);
      const u16* vbase = vt + ((size_t)((b * H_ + h) * 64 + w * 8 + l3)) * S_ + kt * 64 + sb * 8;
      gload_lds16(vbase, &Vts[(w * 8) * 64]);
    }
    __syncthreads();

    f32x4 sf[4] = {};
#pragma unroll
    for (int ks = 0; ks < 2; ++ks) {
      const int kb = ks * 4 + fq;
      __builtin_amdgcn_s_setprio(1);
#pragma unroll
      for (int r4 = 0; r4 < 4; ++r4) {
        bf16x8 kf = ldsfrag(Ks, r4 * 16, fr, kb);
        sf[r4] = __builtin_amdgcn_mfma_f32_16x16x32_bf16(kf, qf[ks], sf[r4], 0, 0, 0);
      }
      __builtin_amdgcn_s_setprio(0);
    }
    if (!ALLV) {
#pragma unroll
      for (int r4 = 0; r4 < 4; ++r4) {
        const int4 mm = *(const int4*)&mask[b * S_ + kt * 64 + r4 * 16 + fq * 4];
        f32x4 vb;
        vb[0] = mm.x ? 0.f : -1e30f;
        vb[1] = mm.y ? 0.f : -1e30f;
        vb[2] = mm.z ? 0.f : -1e30f;
        vb[3] = mm.w ? 0.f : -1e30f;
        sf[r4] += vb;
      }
    }

    {
      u16* pw = PsW + fr * 64;
      float sum = l_st;
#pragma unroll
      for (int r4 = 0; r4 < 4; ++r4) {
        const float p0 = __builtin_exp2f(sf[r4][0]);
        const float p1 = __builtin_exp2f(sf[r4][1]);
        const float p2 = __builtin_exp2f(sf[r4][2]);
        const float p3 = __builtin_exp2f(sf[r4][3]);
        sum += (p0 + p1) + (p2 + p3);
        const int bk0 = 2 * r4 + (fq >> 1);
        const int off = ((bk0 ^ (fr & 7)) << 3) + ((fq & 1) << 2);
        uint2 pk; pk.x = cvtpk(p0, p1); pk.y = cvtpk(p2, p3);
        *(uint2*)&pw[off] = pk;
      }
      l_st = sum;
    }
    asm volatile("s_waitcnt lgkmcnt(0)" ::: "memory");

#pragma unroll
    for (int ks = 0; ks < 2; ++ks) {
      const int kb = ks * 4 + fq;
      bf16x8 pf = ldsfrag(PsW, 0, fr, kb);
      __builtin_amdgcn_s_setprio(1);
#pragma unroll
      for (int db = 0; db < 4; ++db) {
        bf16x8 vf = ldsfrag(Vts, db * 16, fr, kb);
        ot[db] = __builtin_amdgcn_mfma_f32_16x16x32_bf16(vf, pf, ot[db], 0, 0, 0);
      }
      __builtin_amdgcn_s_setprio(0);
    }
    __syncthreads();
  }

  {
    float l = l_st;
    l += __shfl_xor(l, 16);
    l += __shfl_xor(l, 32);
    const float inv = (l > 0.f) ? 1.f / l : 0.f;
    const int qrow = qt * 128 + w * 16 + fr;
    u16* dst = attno + (size_t)(b * S_ + qrow) * D_ + h * 64 + fq * 4;
#pragma unroll
    for (int db = 0; db < 4; ++db) {
      ushort4 pk;
      pk.x = f2bf(ot[db][0] * inv);
      pk.y = f2bf(ot[db][1] * inv);
      pk.z = f2bf(ot[db][2] * inv);
      pk.w = f2bf(ot[db][3] * inv);
      *(ushort4*)&dst[db * 16] = pk;
    }
  }
}

// ---------------------------------------------------------------------------
// LayerNorm(a + res) * g + be  ->  fp32 out (+ optional bf16 copy). (LN1)
template <int WRITEB>
__global__ __launch_bounds__(256) void ln_kernel(const float* __restrict__ a,
                                                 const float* __restrict__ res,
                                                 const float* __restrict__ g,
                                                 const float* __restrict__ be,
                                                 float* __restrict__ outf,
                                                 u16* __restrict__ outb) {
  const int row = blockIdx.x, tid = threadIdx.x;
  const int lane = tid & 63, w = tid >> 6;
  const size_t base = (size_t)row * D_ + tid * 4;
  const f32x4 va = *(const f32x4*)(a + base);
  const f32x4 vr = *(const f32x4*)(res + base);
  const f32x4 v  = va + vr;
  float s = v[0] + v[1] + v[2] + v[3];
#pragma unroll
  for (int o = 32; o > 0; o >>= 1) s += __shfl_xor(s, o);
  __shared__ float red[8];
  if (lane == 0) red[w] = s;
  __syncthreads();
  const float mu = (red[0] + red[1] + red[2] + red[3]) * (1.f / D_);
  const f32x4 d = v - mu;
  float s2 = d[0] * d[0] + d[1] * d[1] + d[2] * d[2] + d[3] * d[3];
#pragma unroll
  for (int o = 32; o > 0; o >>= 1) s2 += __shfl_xor(s2, o);
  if (lane == 0) red[4 + w] = s2;
  __syncthreads();
  const float var = (red[4] + red[5] + red[6] + red[7]) * (1.f / D_);
  const float rs = rsqrtf(var + 1e-5f);
  f32x4 y;
#pragma unroll
  for (int k = 0; k < 4; ++k) {
    const int ch = tid * 4 + k;
    y[k] = d[k] * rs * g[ch] + be[ch];
  }
  *(f32x4*)&outf[base] = y;
  if (WRITEB) {
    ushort4 pk;
    pk.x = f2bf(y[0]); pk.y = f2bf(y[1]); pk.z = f2bf(y[2]); pk.w = f2bf(y[3]);
    *(ushort4*)&outb[base] = pk;
  }
}

// ---------------------------------------------------------------------------
// FUSED LN2 + masked max-pool stage 1. LN2's output feeds ONLY the pool, so
// compute LN per-row fully in-register (ONE ROW PER WAVE: 64 lanes x 16
// elems, pure shfl reductions -- zero barriers in the hot loop) and fold
// straight into the running max. Eliminates LN2's 32MB write + pool's 32MB
// read + one kernel launch.
// Block = (s-chunk of 64, b): 4 waves x 16 rows each. One LDS combine at end.
__global__ __launch_bounds__(256) void lnpool_kernel(const float* __restrict__ a,
                                                     const float* __restrict__ res,
                                                     const float* __restrict__ g,
                                                     const float* __restrict__ be,
                                                     const int* __restrict__ mask,
                                                     float* __restrict__ part) {
  __shared__ float red[4][64 * 16];   // per-wave max slabs (16 KB)
  const int ch = blockIdx.x, b = blockIdx.y;
  const int lane = threadIdx.x & 63, wv = threadIdx.x >> 6;
  // lane's d positions: d = j*256 + lane*4 + k  (coalesced per j)
  f32x4 gg[4], bb[4];
#pragma unroll
  for (int j = 0; j < 4; ++j) {
    gg[j] = *(const f32x4*)&g[j * 256 + lane * 4];
    bb[j] = *(const f32x4*)&be[j * 256 + lane * 4];
  }
  f32x4 acc[4];
#pragma unroll
  for (int j = 0; j < 4; ++j)
    acc[j] = f32x4{-INFINITY, -INFINITY, -INFINITY, -INFINITY};

  for (int r = 0; r < 16; ++r) {
    const int s = ch * 64 + r * 4 + wv;
    const size_t base = (size_t)(b * S_ + s) * D_ + lane * 4;
    f32x4 v[4];
    float sum = 0.f;
#pragma unroll
    for (int j = 0; j < 4; ++j) {
      const f32x4 va = *(const f32x4*)(a + base + j * 256);
      const f32x4 vr = *(const f32x4*)(res + base + j * 256);
      v[j] = va + vr;
      sum += (v[j][0] + v[j][1]) + (v[j][2] + v[j][3]);
    }
#pragma unroll
    for (int o = 32; o > 0; o >>= 1) sum += __shfl_xor(sum, o);
    const float mu = sum * (1.f / D_);
    float s2 = 0.f;
#pragma unroll
    for (int j = 0; j < 4; ++j) {
      v[j] = v[j] - mu;
      s2 += (v[j][0] * v[j][0] + v[j][1] * v[j][1]) +
            (v[j][2] * v[j][2] + v[j][3] * v[j][3]);
    }
#pragma unroll
    for (int o = 32; o > 0; o >>= 1) s2 += __shfl_xor(s2, o);
    const float rs = rsqrtf(s2 * (1.f / D_) + 1e-5f);
    if (mask[b * S_ + s] != 0) {
#pragma unroll
      for (int j = 0; j < 4; ++j) {
        f32x4 y = v[j] * rs * gg[j] + bb[j];
        acc[j][0] = fmaxf(acc[j][0], y[0]);
        acc[j][1] = fmaxf(acc[j][1], y[1]);
        acc[j][2] = fmaxf(acc[j][2], y[2]);
        acc[j][3] = fmaxf(acc[j][3], y[3]);
      }
    }
  }

  // combine the 4 waves' maxes: wave wv's slab holds d = j*256+lane*4+k at
  // [lane*16 + j*4 + k]; thread (wv,lane) then owns j=wv for its lane.
#pragma unroll
  for (int j = 0; j < 4; ++j)
    *(f32x4*)&red[wv][lane * 16 + j * 4] = acc[j];
  __syncthreads();
  f32x4 m = *(const f32x4*)&red[0][lane * 16 + wv * 4];
#pragma unroll
  for (int w2 = 1; w2 < 4; ++w2) {
    const f32x4 o = *(const f32x4*)&red[w2][lane * 16 + wv * 4];
    m[0] = fmaxf(m[0], o[0]); m[1] = fmaxf(m[1], o[1]);
    m[2] = fmaxf(m[2], o[2]); m[3] = fmaxf(m[3], o[3]);
  }
  *(f32x4*)&part[(size_t)(b * 32 + ch) * D_ + wv * 256 + lane * 4] = m;
}

__global__ __launch_bounds__(256) void pool_final_kernel(const float* __restrict__ part,
                                                         float* __restrict__ pooled) {
  const int b = blockIdx.x;
  const int d0 = threadIdx.x * 4;
  f32x4 acc = {-INFINITY, -INFINITY, -INFINITY, -INFINITY};
  for (int ch = 0; ch < 32; ++ch) {
    const f32x4 v = *(const f32x4*)&part[(size_t)(b * 32 + ch) * D_ + d0];
    acc[0] = fmaxf(acc[0], v[0]);
    acc[1] = fmaxf(acc[1], v[1]);
    acc[2] = fmaxf(acc[2], v[2]);
    acc[3] = fmaxf(acc[3], v[3]);
  }
  *(f32x4*)&pooled[(size_t)b * D_ + d0] = acc;
}

// ---------------------------------------------------------------------------
// tiny head GEMMs in fp32, one wave per output element
__global__ __launch_bounds__(256) void head1_kernel(const float* __restrict__ pooled,
                                                    const float* __restrict__ w,
                                                    const float* __restrict__ bias,
                                                    float* __restrict__ hh) {
  const int lane = threadIdx.x & 63;
  const int gw = blockIdx.x * 4 + (threadIdx.x >> 6);
  const int b = gw >> 10, n = gw & 1023;
  const float* p  = pooled + b * 1024;
  const float* wr = w + (size_t)n * 1024;
  float s = 0.f;
  for (int d = lane; d < 1024; d += 64) s += p[d] * wr[d];
#pragma unroll
  for (int off = 32; off > 0; off >>= 1) s += __shfl_xor(s, off);
  if (lane == 0) hh[b * 1024 + n] = gelu_f(s + bias[n]);
}
__global__ __launch_bounds__(256) void head2_kernel(const float* __restrict__ hh,
                                                    const float* __restrict__ w,
                                                    const float* __restrict__ bias,
                                                    float* __restrict__ out) {
  const int lane = threadIdx.x & 63;
  const int gw = blockIdx.x * 4 + (threadIdx.x >> 6);  // 0..39
  const int b = gw / 10, c = gw % 10;
  const float* p  = hh + b * 1024;
  const float* wr = w + (size_t)c * 1024;
  float s = 0.f;
  for (int d = lane; d < 1024; d += 64) s += p[d] * wr[d];
#pragma unroll
  for (int off = 32; off > 0; off >>= 1) s += __shfl_xor(s, off);
  if (lane == 0) out[b * 10 + c] = s + bias[c];
}

// ---------------------------------------------------------------------------
// workspace layout (bytes)
#define OFF_RESID  0UL                      // 32 MB fp32 [M,D]
#define OFF_F1     33554432UL               // 32 MB fp32 [M,D]  (alias: vt 16MB)
#define OFF_XB     67108864UL               // 16 MB bf16 [M,D]
#define OFF_QKVB   83886080UL               // 48 MB bf16 [M,3D] (alias: hb 32MB)
#define OFF_ATTNO  134217728UL              // 16 MB bf16 [M,D]
#define OFF_WQKV   150994944UL              // 6 MB
#define OFF_WFC    157286400UL              // 2 MB
#define OFF_WF1    159383552UL              // 4 MB
#define OFF_WF2    163577856UL              // 4 MB
#define OFF_PART   167772160UL              // 512 KB
#define OFF_POOLED 168296448UL              // 16 KB
#define OFF_HH     168312832UL              // 16 KB  (end ~160.6 MB)

extern "C" void kernel_launch(void* const* d_in, const int* in_sizes, int n_in,
                              void* d_out, int out_size, void* d_ws, size_t ws_size,
                              hipStream_t stream) {
  const int*   x_ids  = (const int*)d_in[0];
  const int*   mask   = (const int*)d_in[1];
  const float* emb    = (const float*)d_in[2];
  const float* qkv_w  = (const float*)d_in[3];
  const float* fc_w   = (const float*)d_in[4];
  const float* fc_b   = (const float*)d_in[5];
  const float* ln1_g  = (const float*)d_in[6];
  const float* ln1_b  = (const float*)d_in[7];
  const float* ffn_w1 = (const float*)d_in[8];
  const float* ffn_b1 = (const float*)d_in[9];
  const float* ffn_w2 = (const float*)d_in[10];
  const float* ffn_b2 = (const float*)d_in[11];
  const float* ln2_g  = (const float*)d_in[12];
  const float* ln2_b  = (const float*)d_in[13];
  const float* pr_w1  = (const float*)d_in[14];
  const float* pr_b1  = (const float*)d_in[15];
  const float* pr_w2  = (const float*)d_in[16];
  const float* pr_b2  = (const float*)d_in[17];
  float* out = (float*)d_out;
  char* ws = (char*)d_ws;

  float* resid  = (float*)(ws + OFF_RESID);
  float* f1     = (float*)(ws + OFF_F1);
  u16*   vtb    = (u16*)(ws + OFF_F1);     // alias (dead before f1 written)
  u16*   xb     = (u16*)(ws + OFF_XB);
  u16*   qkvb   = (u16*)(ws + OFF_QKVB);
  u16*   hb     = (u16*)(ws + OFF_QKVB);   // alias
  u16*   attnob = (u16*)(ws + OFF_ATTNO);
  u16*   wqkvb  = (u16*)(ws + OFF_WQKV);
  u16*   wfcb   = (u16*)(ws + OFF_WFC);
  u16*   wf1b   = (u16*)(ws + OFF_WF1);
  u16*   wf2b   = (u16*)(ws + OFF_WF2);
  float* part   = (float*)(ws + OFF_PART);
  float* pooled = (float*)(ws + OFF_POOLED);
  float* hh     = (float*)(ws + OFF_HH);

  // weights fp32 -> bf16 + embed/posenc (single fused launch)
  prep_kernel<<<16384, 256, 0, stream>>>(qkv_w, fc_w, ffn_w1, ffn_w2,
                                         wqkvb, wfcb, wf1b, wf2b,
                                         x_ids, emb, resid, xb);

  // QKV projection (Q pre-scaled by EXPSCL); V columns written transposed
  gemm_bt<0, 0, 1, 1, 1><<<dim3(D3_ / 128, M_ / 128), 256, 0, stream>>>(
      xb, wqkvb, nullptr, nullptr, qkvb, vtb, M_, D3_, D_);

  attn_mfma_kernel<<<dim3(S_ / 128, H_, B_), 512, 0, stream>>>(qkvb, vtb, mask, attnob);

  // out proj (+bias) -> fp32
  gemm_bt<1, 0, 0, 0, 0><<<dim3(D_ / 128, M_ / 128), 256, 0, stream>>>(
      attnob, wfcb, fc_b, f1, nullptr, nullptr, M_, D_, D_);

  // LN1(fc_out + resid) -> resid (fp32) + xb (bf16)
  ln_kernel<1><<<M_, 256, 0, stream>>>(f1, resid, ln1_g, ln1_b, resid, xb);

  // FFN1 (+bias, gelu) -> bf16 hb
  gemm_bt<1, 1, 1, 0, 0><<<dim3(FFN_ / 128, M_ / 128), 256, 0, stream>>>(
      xb, wf1b, ffn_b1, nullptr, hb, nullptr, M_, FFN_, D_);

  // FFN2 (+bias) -> fp32 f1
  gemm_bt<1, 0, 0, 0, 0><<<dim3(D_ / 128, M_ / 128), 256, 0, stream>>>(
      hb, wf2b, ffn_b2, f1, nullptr, nullptr, M_, D_, FFN_);

  // FUSED LN2 + masked max-pool stage 1 (LN2 output never materialized)
  lnpool_kernel<<<dim3(32, B_), 256, 0, stream>>>(f1, resid, ln2_g, ln2_b,
                                                  mask, part);
  pool_final_kernel<<<B_, 256, 0, stream>>>(part, pooled);

  // prediction head (fp32)
  head1_kernel<<<1024, 256, 0, stream>>>(pooled, pr_w1, pr_b1, hh);
  head2_kernel<<<10, 256, 0, stream>>>(hh, pr_w2, pr_b2, out);
}